// Round 9
// baseline (116.944 us; speedup 1.0000x reference)
//
#include <hip/hip_runtime.h>
#include <hip/hip_fp8.h>
#include <stdint.h>
#include <math.h>

#define C_NUM 2048
#define N_TOT 4096
#define B_TOT 4096
#define KNOWN 1024

typedef __attribute__((ext_vector_type(16))) float f32x16;
typedef __attribute__((ext_vector_type(4))) int i32x4;
typedef __attribute__((ext_vector_type(8))) int i32x8;

__device__ __forceinline__ void gld16(const void* g, void* l) {
  __builtin_amdgcn_global_load_lds(
      (const __attribute__((address_space(1))) void*)g,
      (__attribute__((address_space(3))) void*)l, 16, 0, 0);
}

// ---- Kernel 1: transpose + fp8(e4m3) convert + colsum/norm2 partials -----
__global__ void transpose_stats_kernel(const float* __restrict__ prob,
                                       const float* __restrict__ prob_s,
                                       float* __restrict__ colsum,
                                       float* __restrict__ norm2,
                                       uint8_t* __restrict__ Pn) {
  __shared__ float tile[64][65];
  int tx = threadIdx.x;          // 0..63
  int ty = threadIdx.y;          // 0..3
  int c0 = blockIdx.x * 64;      // class tile (0..4095)
  int b0 = blockIdx.y * 64;      // batch tile
  const float* src = (c0 < C_NUM) ? prob : prob_s;
  int colbase = (c0 & (C_NUM - 1)) + tx;
  float s = 0.f, s2 = 0.f;
#pragma unroll
  for (int r = 0; r < 16; ++r) {
    int b = b0 + r * 4 + ty;
    float v = src[(size_t)b * C_NUM + colbase];
    tile[r * 4 + ty][tx] = v;
    s += v;
    s2 += v * v;
  }
  atomicAdd(&colsum[c0 + tx], s);
  atomicAdd(&norm2[c0 + tx], s2);
  __syncthreads();
#pragma unroll
  for (int r = 0; r < 16; ++r) {
    int i = c0 + r * 4 + ty;
    __hip_fp8_e4m3 q(tile[tx][r * 4 + ty]);
    Pn[(size_t)i * B_TOT + b0 + tx] = q.__x;
  }
}

// ---- Kernel 2: invn[i] = 1/max(||P_i||, eps) ------------------------------
__global__ void invnorm_kernel(const float* __restrict__ norm2,
                               float* __restrict__ invn) {
  int i = blockIdx.x * 256 + threadIdx.x;
  invn[i] = 1.0f / fmaxf(sqrtf(norm2[i]), 1e-8f);
}

// ---- Kernel 3: symmetric MX-fp8 GEMM (32x32x64) + softmax epilogue -------
// 128x128 tile, 256 threads = 4 waves (2x2 grid), per-wave 64x64 output =
// acc[2][2] of mfma_scale_f32_32x32x64_f8f6f4 (unit E8M0 scales).
// BK=64 bytes; 3-buffer LDS ring (3 x 16 KB), counted vmcnt(4), one raw
// barrier per step, stage-ahead-2 (latency cover = 2 iterations).
// Granule swizzle: 16B granule g of row r stored at phys (g + r) & 3
// (pre-permuted global source, linear gld_lds dest; same map on ds_read).
// Triangular job grid (jt >= it, 528 jobs) with bijective XCD chunking.
__global__ __launch_bounds__(256, 3) void simgemm_kernel(
    const uint8_t* __restrict__ Pn,
    const float* __restrict__ invn,
    float* __restrict__ sumexp,
    float* __restrict__ pos) {
  __shared__ __align__(16) char lds[49152];  // buf q at q*16384: A +0, B +8192

  const int tid = threadIdx.x;
  const int l = tid & 63;
  const int w = tid >> 6;            // wave 0..3
  const int wr = w >> 1, wc = w & 1; // 2x2 wave grid

  // XCD-chunked bijective job swizzle: 528 = 8 * 66
  const int job = (blockIdx.x & 7) * 66 + (blockIdx.x >> 3);
  int t = job;
  int it = 0, rem = 32;
  while (t >= rem) { t -= rem; ++it; --rem; }
  const int jt = it + t;
  const int ib = it * 128;
  const int jb = jt * 128;

  // staging: thread tid covers granules G=tid (rows 0..63) and G=tid+256
  // (rows 64..127) of both A and B tiles. G: row=G>>2, phys g=G&3,
  // logical = (g - row) & 3 -> pre-permuted global column. (tid+256: row+64,
  // 64%4==0 -> same logical granule.)
  const int r0 = tid >> 2;
  const int g0 = ((tid & 3) - r0) & 3;
  const char* gA = (const char*)Pn + (size_t)(ib + r0) * B_TOT + g0 * 16;
  const char* gB = (const char*)Pn + (size_t)(jb + r0) * B_TOT + g0 * 16;
  const int ldsOf = tid * 16;

  f32x16 acc[2][2] = {{{}, {}}, {{}, {}}};

  // fragment read geometry: rows of 64B (BK=64), lane l reads 32B of K at
  // logical granules gl=2*(l>>5), gl+1; phys = (glog + row) & 3.
  const int lr = l & 31;
  const int gl = (l >> 5) * 2;
  const int ra = wr * 64 + lr;           // + a*32 (a*32 % 4 == 0: same phys)
  const int rb = wc * 64 + lr;           // + b*32
  const int pa0 = (gl + ra) & 3, pa1 = (gl + 1 + ra) & 3;
  const int pb0 = (gl + rb) & 3, pb1 = (gl + 1 + rb) & 3;

#define STAGE(buf, koff)                                                   \
  do {                                                                     \
    gld16(gA + (koff), lds + (buf) * 16384 + ldsOf);                       \
    gld16(gA + (size_t)64 * B_TOT + (koff), lds + (buf) * 16384 + 4096 + ldsOf); \
    gld16(gB + (koff), lds + (buf) * 16384 + 8192 + ldsOf);                \
    gld16(gB + (size_t)64 * B_TOT + (koff), lds + (buf) * 16384 + 12288 + ldsOf); \
  } while (0)

#define LOAD_FRAGS(cur)                                                    \
  do {                                                                     \
    const char* Abase = lds + (cur) * 16384;                               \
    const char* Bbase = Abase + 8192;                                      \
    _Pragma("unroll")                                                      \
    for (int a = 0; a < 2; ++a) {                                          \
      const char* p = Abase + (ra + a * 32) * 64;                          \
      i32x4 lo = *(const i32x4*)(p + pa0 * 16);                            \
      i32x4 hi = *(const i32x4*)(p + pa1 * 16);                            \
      af[a] = __builtin_shufflevector(lo, hi, 0, 1, 2, 3, 4, 5, 6, 7);     \
    }                                                                      \
    _Pragma("unroll")                                                      \
    for (int b = 0; b < 2; ++b) {                                          \
      const char* p = Bbase + (rb + b * 32) * 64;                          \
      i32x4 lo = *(const i32x4*)(p + pb0 * 16);                            \
      i32x4 hi = *(const i32x4*)(p + pb1 * 16);                            \
      bf[b] = __builtin_shufflevector(lo, hi, 0, 1, 2, 3, 4, 5, 6, 7);     \
    }                                                                      \
  } while (0)

#define DO_MFMA()                                                          \
  do {                                                                     \
    __builtin_amdgcn_s_setprio(1);                                         \
    _Pragma("unroll")                                                      \
    for (int a = 0; a < 2; ++a)                                            \
      _Pragma("unroll")                                                    \
      for (int b = 0; b < 2; ++b)                                          \
        acc[a][b] = __builtin_amdgcn_mfma_scale_f32_32x32x64_f8f6f4(       \
            af[a], bf[b], acc[a][b], 0, 0, 0, 0x7F7F7F7F, 0, 0x7F7F7F7F);  \
    __builtin_amdgcn_s_setprio(0);                                         \
  } while (0)

  const int NT = B_TOT / 64;   // 64 K-steps of 64 bytes
  // prologue: stage tiles 0 and 1
  STAGE(0, 0);
  STAGE(1, 64);

  int cur = 0;
  for (int kt = 0; kt < NT - 1; ++kt) {
    i32x8 af[2], bf[2];
    // tile kt resident across ALL waves: own vmcnt(4) then barrier
    asm volatile("s_waitcnt vmcnt(4)" ::: "memory");
    __builtin_amdgcn_sched_barrier(0);
    __builtin_amdgcn_s_barrier();
    // stage tile kt+2 into the buffer retired at iter kt-1 (safe: its
    // reads were consumed before that wave's iter-kt barrier)
    if (kt + 2 < NT) {
      int bs = cur + 2; if (bs >= 3) bs -= 3;
      STAGE(bs, (size_t)(kt + 2) * 64);
    }
    LOAD_FRAGS(cur);
    DO_MFMA();
    ++cur; if (cur == 3) cur = 0;
  }
  {  // peeled last iteration: full drain
    i32x8 af[2], bf[2];
    asm volatile("s_waitcnt vmcnt(0)" ::: "memory");
    __builtin_amdgcn_sched_barrier(0);
    __builtin_amdgcn_s_barrier();
    LOAD_FRAGS(cur);
    DO_MFMA();
  }
#undef STAGE
#undef LOAD_FRAGS
#undef DO_MFMA

  // ---- epilogue: v = 2*dot*invn[i]*invn[j]; uniform j>i rule, dual acc ----
  // C/D layout (32x32): col = l&31, row = (reg&3) + 8*(reg>>2) + 4*(l>>5)
  const int hi = l >> 5;
  float invj[2];
#pragma unroll
  for (int b = 0; b < 2; ++b)
    invj[b] = invn[jb + wc * 64 + b * 32 + lr];

  float cs[2] = {0.f, 0.f};
#pragma unroll
  for (int a = 0; a < 2; ++a) {
#pragma unroll
    for (int reg = 0; reg < 16; ++reg) {
      const int i = ib + wr * 64 + a * 32 + (reg & 3) + 8 * (reg >> 2) + 4 * hi;
      const float invi = invn[i];
      float rs = 0.f;
#pragma unroll
      for (int b = 0; b < 2; ++b) {
        const int j = jb + wc * 64 + b * 32 + lr;
        float v = acc[a][b][reg] * 2.0f * invi * invj[b];
        if (j > i) {
          if (j == (i ^ 2048)) {
            pos[i] = v;
            pos[j] = v;
          } else {
            float e = __expf(v);
            rs += (((i & 1024) == 0) && (j < KNOWN)) ? 1.0f : e;
            cs[b] += (((j & 1024) == 0) && (i < KNOWN)) ? 1.0f : e;
          }
        }
      }
      rs += __shfl_xor(rs, 1);
      rs += __shfl_xor(rs, 2);
      rs += __shfl_xor(rs, 4);
      rs += __shfl_xor(rs, 8);
      rs += __shfl_xor(rs, 16);
      if (lr == 0 && rs != 0.f) atomicAdd(&sumexp[i], rs);
    }
  }
#pragma unroll
  for (int b = 0; b < 2; ++b) {
    cs[b] += __shfl_xor(cs[b], 32);
    if (l < 32 && cs[b] != 0.f)
      atomicAdd(&sumexp[jb + wc * 64 + b * 32 + l], cs[b]);
  }
}

// ---- Kernel 4: finalize ---------------------------------------------------
__device__ float block_reduce_256(float v, volatile float* red) {
#pragma unroll
  for (int m = 32; m >= 1; m >>= 1) v += __shfl_xor(v, m);
  __syncthreads();
  if ((threadIdx.x & 63) == 0) red[threadIdx.x >> 6] = v;
  __syncthreads();
  return red[0] + red[1] + red[2] + red[3];
}

__global__ void finalize_kernel(const float* __restrict__ colsum,
                                const float* __restrict__ sumexp,
                                const float* __restrict__ pos,
                                float* __restrict__ out) {
  __shared__ float red[4];
  int t = threadIdx.x;
  float ce = 0.f, t1 = 0.f, t2 = 0.f;
  for (int i = t; i < N_TOT; i += 256) ce += logf(sumexp[i]) - pos[i];
  for (int c = t; c < C_NUM; c += 256) t1 += colsum[c];
  for (int c = t; c < C_NUM; c += 256) t2 += colsum[C_NUM + c];
  ce = block_reduce_256(ce, red);
  t1 = block_reduce_256(t1, red);
  t2 = block_reduce_256(t2, red);
  float e1 = 0.f, e2 = 0.f;
  for (int c = t; c < C_NUM; c += 256) {
    float m = colsum[c] / t1;
    e1 += m * logf(m);
  }
  for (int c = t; c < C_NUM; c += 256) {
    float m = colsum[C_NUM + c] / t2;
    e2 += m * logf(m);
  }
  e1 = block_reduce_256(e1, red);
  e2 = block_reduce_256(e2, red);
  if (t == 0) {
    float reg = logf((float)C_NUM) + e1 + logf((float)C_NUM) + e2;
    out[0] = ce / (float)N_TOT + reg;
  }
}

extern "C" void kernel_launch(void* const* d_in, const int* in_sizes, int n_in,
                              void* d_out, int out_size, void* d_ws, size_t ws_size,
                              hipStream_t stream) {
  const float* prob = (const float*)d_in[0];
  const float* prob_s = (const float*)d_in[1];
  float* out = (float*)d_out;

  char* ws = (char*)d_ws;
  uint8_t* Pn = (uint8_t*)ws;                                   // 16 MB fp8
  float* norm2 = (float*)(ws + (size_t)N_TOT * B_TOT);          // 4096 f32
  float* colsum = norm2 + N_TOT;                                // 4096 f32
  float* sumexp = colsum + N_TOT;                               // 4096 f32
  float* invn = sumexp + N_TOT;                                 // 4096 f32
  float* pos = invn + N_TOT;                                    // 4096 f32

  // zero the atomic accumulators (norm2, colsum, sumexp contiguous)
  hipMemsetAsync(norm2, 0, (size_t)3 * N_TOT * sizeof(float), stream);

  transpose_stats_kernel<<<dim3(64, 64), dim3(64, 4), 0, stream>>>(
      prob, prob_s, colsum, norm2, Pn);
  invnorm_kernel<<<16, 256, 0, stream>>>(norm2, invn);
  simgemm_kernel<<<528, 256, 0, stream>>>(Pn, invn, sumexp, pos);
  finalize_kernel<<<1, 256, 0, stream>>>(colsum, sumexp, pos, out);
}